// Round 1
// baseline (193.809 us; speedup 1.0000x reference)
//
#include <hip/hip_runtime.h>
#include <hip/hip_bf16.h>
#include <math.h>

// ---------------------------------------------------------------------------
// CrossModalityMultiHeadAttention  (MI355X / gfx950)
// Round 8: restructure the dispatch graph (gemm128 main loop untouched).
//   - D1: prep + ALL weight transposes + map_w bf16 cast + bias-fold merged
//     into one z-plane dispatch (independent jobs, were 2 dispatches)
//   - algebraic map-fold via MFMA: FqT = q1T @ mapw_bf^T  (tiny 36-block
//     GEMM) removes the map GEMM from the 4096-row critical path; head qkv
//     now reads h_head_bf directly with Kp=320.
//     (round-6's fold regression was the register-prefetch restructure that
//      broke the XOR swizzle — here the proven inner loop is IDENTICAL,
//      only the epilogue gains ldC/Ncol for the [512][320] fold output.)
//   - all 6 qkv GEMMs in ONE 768-block dispatch (was 512 + 384 serialized)
// Dispatches: prep+trans, fold(z=3), qkv(z=6), attn(z=2), out(z=2) = 5
// ---------------------------------------------------------------------------

typedef __bf16 bf16x8 __attribute__((ext_vector_type(8)));
typedef float  f32x4  __attribute__((ext_vector_type(4)));

#define HID 512
#define NTOK 4096

#define AS1(p) ((const __attribute__((address_space(1))) void*)(p))
#define AS3(p) ((__attribute__((address_space(3))) void*)(p))

// --------------------- fused prep / transpose / cast -----------------------
// grid (512, 1, 11):
//   z=0 : h_head fp32 -> hh_bf [4096][320] (pad 300..319 = 0) + ranges
//   z=1 : h_tail fp32 -> ht_bf [4096][512]
//   z=2 : q<96  : map_w fp32 -> mapw_bf [384][512] (rows 300..383 = 0)
//         q<102 : fused bias fb[w][n] = sum_j map_b[j]*W[j][n] + b[n]
//   z=3..10 : weight transpose W[512][512] fp32 -> WT[512][512] bf16
//             (q1,k1,v1,q2,k2,v2,d1,d2); blocks q<64, tile (q&7, q>>3)
struct PrepArgs {
    const float* h_head; const float* h_tail;
    const int* bh; const int* bt;
    const float* map_w; const float* map_b;
    const float* qkvw[3]; const float* qkvb[3];
    const float* tsrc[8]; __bf16* tdst[8];
    __bf16* hh_bf; __bf16* ht_bf; __bf16* mapw_bf;
    float* fb;            // [3][512] fp32
    int* ranges;
};

__global__ __launch_bounds__(256) void fused_prep(PrepArgs pa) {
    const int q = blockIdx.x, z = blockIdx.z, tid = threadIdx.x;
    __shared__ __bf16 T[64][72];

    if (z == 0) {
        if (q == 0 && tid < 128) {
            int b = tid & 63;
            const int* arr = (tid < 64) ? pa.bh : pa.bt;
            int base = (tid < 64) ? 0 : 128;
            int lo = 0, hi = NTOK;
            while (lo < hi) { int mid = (lo + hi) >> 1; if (arr[mid] < b) lo = mid + 1; else hi = mid; }
            int start = lo;
            lo = 0; hi = NTOK;
            while (lo < hi) { int mid = (lo + hi) >> 1; if (arr[mid] <= b) lo = mid + 1; else hi = mid; }
            pa.ranges[base + b] = start;
            pa.ranges[base + 64 + b] = lo;
        }
        // head: 8 rows x 40 chunks (src 300 cols, dst 320)
        for (int idx = tid; idx < 8 * 40; idx += 256) {
            int r   = q * 8 + idx / 40;
            int col = (idx % 40) * 8;
            bf16x8 v;
            if (col + 8 <= 300) {
                float4 f0 = *(const float4*)&pa.h_head[(size_t)r * 300 + col];
                float4 f1 = *(const float4*)&pa.h_head[(size_t)r * 300 + col + 4];
                v[0]=(__bf16)f0.x; v[1]=(__bf16)f0.y; v[2]=(__bf16)f0.z; v[3]=(__bf16)f0.w;
                v[4]=(__bf16)f1.x; v[5]=(__bf16)f1.y; v[6]=(__bf16)f1.z; v[7]=(__bf16)f1.w;
            } else if (col < 300) {  // col == 296: 4 valid + 4 pad
                float4 f0 = *(const float4*)&pa.h_head[(size_t)r * 300 + col];
                v[0]=(__bf16)f0.x; v[1]=(__bf16)f0.y; v[2]=(__bf16)f0.z; v[3]=(__bf16)f0.w;
                v[4]=(__bf16)0.f; v[5]=(__bf16)0.f; v[6]=(__bf16)0.f; v[7]=(__bf16)0.f;
            } else {
                #pragma unroll
                for (int j = 0; j < 8; ++j) v[j] = (__bf16)0.f;
            }
            *(bf16x8*)&pa.hh_bf[(size_t)r * 320 + col] = v;
        }
    } else if (z == 1) {
        for (int idx = tid; idx < 8 * 64; idx += 256) {
            int r   = q * 8 + (idx >> 6);
            int col = (idx & 63) * 8;
            float4 f0 = *(const float4*)&pa.h_tail[(size_t)r * 512 + col];
            float4 f1 = *(const float4*)&pa.h_tail[(size_t)r * 512 + col + 4];
            bf16x8 v;
            v[0]=(__bf16)f0.x; v[1]=(__bf16)f0.y; v[2]=(__bf16)f0.z; v[3]=(__bf16)f0.w;
            v[4]=(__bf16)f1.x; v[5]=(__bf16)f1.y; v[6]=(__bf16)f1.z; v[7]=(__bf16)f1.w;
            *(bf16x8*)&pa.ht_bf[(size_t)r * 512 + col] = v;
        }
    } else if (z == 2) {
        if (q < 96) {
            // map_w bf16 cast, 4 rows/block, zero-pad rows >= 300
            int r   = q * 4 + (tid >> 6);
            int col = (tid & 63) * 8;
            bf16x8 v;
            if (r < 300) {
                float4 f0 = *(const float4*)&pa.map_w[(size_t)r * 512 + col];
                float4 f1 = *(const float4*)&pa.map_w[(size_t)r * 512 + col + 4];
                v[0]=(__bf16)f0.x; v[1]=(__bf16)f0.y; v[2]=(__bf16)f0.z; v[3]=(__bf16)f0.w;
                v[4]=(__bf16)f1.x; v[5]=(__bf16)f1.y; v[6]=(__bf16)f1.z; v[7]=(__bf16)f1.w;
            } else {
                #pragma unroll
                for (int j = 0; j < 8; ++j) v[j] = (__bf16)0.f;
            }
            *(bf16x8*)&pa.mapw_bf[(size_t)r * 512 + col] = v;
        } else if (q < 102) {
            // fused bias: fb[w][n] = map_b . W[:,n] + b[n]   (fp32 exact)
            int b2 = q - 96;
            int w  = b2 >> 1;
            int n  = ((b2 & 1) << 8) + tid;
            const float* W = pa.qkvw[w];
            float s = pa.qkvb[w][n];
            for (int j = 0; j < 512; ++j)
                s += pa.map_b[j] * W[(size_t)j * 512 + n];
            pa.fb[w * 512 + n] = s;
        }
    } else {
        if (q >= 64) return;
        const int jz = z - 3;
        const float* src = pa.tsrc[jz];
        __bf16* dst = pa.tdst[jz];
        const int tk = (q >> 3) * 64;
        const int tn = (q & 7) * 64;
        const int r0 = tid >> 4;
        const int c0 = (tid & 15) * 4;
        #pragma unroll
        for (int i = 0; i < 4; ++i) {
            float4 v = *(const float4*)&src[(size_t)(tk + r0 + i * 16) * 512 + tn + c0];
            T[r0 + i * 16][c0 + 0] = (__bf16)v.x;
            T[r0 + i * 16][c0 + 1] = (__bf16)v.y;
            T[r0 + i * 16][c0 + 2] = (__bf16)v.z;
            T[r0 + i * 16][c0 + 3] = (__bf16)v.w;
        }
        __syncthreads();
        const int n  = tid >> 2;
        const int kk = (tid & 3) * 16;
        bf16x8 o0, o1;
        #pragma unroll
        for (int j = 0; j < 8; ++j) { o0[j] = T[kk + j][n]; o1[j] = T[kk + 8 + j][n]; }
        __bf16* dp = dst + (size_t)(tn + n) * 512 + tk + kk;
        *(bf16x8*)dp       = o0;
        *(bf16x8*)(dp + 8) = o1;
    }
}

// ------------------------------ GEMM 128x128 -------------------------------
// C = A[M,Kp]bf16 @ W[N,Kp]bf16^T + bias; z = job select.
// Main loop identical to round 7 (double-buffered global_load_lds + XOR
// swizzle). Epilogue parameterized by ldC/Ncol so the same kernel emits the
// [512][320] fused-weight tiles (grid x=3, cols >=320 masked).
struct GemmJobs {
    const __bf16* A[6];
    const __bf16* W[6];
    const float*  bias[6];
    void*         C[6];
    int           Kp[6];
    int           ldC[6];
    int           Ncol[6];
};

template <typename TC>
__global__ __launch_bounds__(256) void gemm128(GemmJobs jobs) {
    __shared__ __align__(16) __bf16 As[2][4096];   // 2 x [128][32]
    __shared__ __align__(16) __bf16 Bs[2][4096];

    const int z = blockIdx.z;
    const __bf16* A    = jobs.A[z];
    const __bf16* W    = jobs.W[z];
    const float*  bias = jobs.bias[z];
    TC*           C    = (TC*)jobs.C[z];
    const int     Kp   = jobs.Kp[z];

    const int tid  = threadIdx.x;
    const int wave = tid >> 6;
    const int lane = tid & 63;
    const int quad = lane >> 4;
    const int l16  = lane & 15;
    const int wy   = wave >> 1;
    const int wx   = wave & 1;
    const int rowBase = blockIdx.y * 128;
    const int colBase = blockIdx.x * 128;

    const int s_row = tid >> 2;
    const int s_kc  = ((tid & 3) ^ ((s_row >> 1) & 3)) * 8;

    const __bf16* gA = A + (size_t)(rowBase + s_row) * Kp + s_kc;
    const __bf16* gB = W + (size_t)(colBase + s_row) * Kp + s_kc;
    const int waveOff = wave * 512;

    f32x4 acc[4][4] = {};
    const int nk = Kp >> 5;

    // preload tile 0 -> buffer 0
    __builtin_amdgcn_global_load_lds(AS1(gA),                   AS3(&As[0][waveOff]),        16, 0, 0);
    __builtin_amdgcn_global_load_lds(AS1(gA + (size_t)64 * Kp), AS3(&As[0][2048 + waveOff]), 16, 0, 0);
    __builtin_amdgcn_global_load_lds(AS1(gB),                   AS3(&Bs[0][waveOff]),        16, 0, 0);
    __builtin_amdgcn_global_load_lds(AS1(gB + (size_t)64 * Kp), AS3(&Bs[0][2048 + waveOff]), 16, 0, 0);

    for (int i = 0; i < nk; ++i) {
        const int cur = i & 1;
        __syncthreads();   // drains tile i's loads; prev reads of buf[cur^1] done

        if (i + 1 < nk) {  // issue tile i+1 into the other buffer
            const int kt = (i + 1) * 32;
            const int nx = cur ^ 1;
            __builtin_amdgcn_global_load_lds(AS1(gA + kt),                   AS3(&As[nx][waveOff]),        16, 0, 0);
            __builtin_amdgcn_global_load_lds(AS1(gA + kt + (size_t)64 * Kp), AS3(&As[nx][2048 + waveOff]), 16, 0, 0);
            __builtin_amdgcn_global_load_lds(AS1(gB + kt),                   AS3(&Bs[nx][waveOff]),        16, 0, 0);
            __builtin_amdgcn_global_load_lds(AS1(gB + kt + (size_t)64 * Kp), AS3(&Bs[nx][2048 + waveOff]), 16, 0, 0);
        }

        bf16x8 ar[4], br[4];
        #pragma unroll
        for (int ii = 0; ii < 4; ++ii) {
            const int ra = wy * 64 + ii * 16 + l16;
            ar[ii] = *(const bf16x8*)&As[cur][ra * 32 + ((quad ^ ((ra >> 1) & 3)) << 3)];
        }
        #pragma unroll
        for (int jj = 0; jj < 4; ++jj) {
            const int rb = wx * 64 + jj * 16 + l16;
            br[jj] = *(const bf16x8*)&Bs[cur][rb * 32 + ((quad ^ ((rb >> 1) & 3)) << 3)];
        }
        #pragma unroll
        for (int ii = 0; ii < 4; ++ii)
            #pragma unroll
            for (int jj = 0; jj < 4; ++jj)
                acc[ii][jj] = __builtin_amdgcn_mfma_f32_16x16x32_bf16(ar[ii], br[jj], acc[ii][jj], 0, 0, 0);
    }

    // epilogue: C/D layout col=l16, row=quad*4+reg
    const int ldC  = jobs.ldC[z];
    const int Ncol = jobs.Ncol[z];
    #pragma unroll
    for (int jj = 0; jj < 4; ++jj) {
        int col = colBase + wx * 64 + jj * 16 + l16;
        if (col < Ncol) {
            float bv = bias ? bias[col] : 0.f;
            #pragma unroll
            for (int ii = 0; ii < 4; ++ii) {
                #pragma unroll
                for (int r = 0; r < 4; ++r) {
                    int row = rowBase + wy * 64 + ii * 16 + quad * 4 + r;
                    C[(size_t)row * ldC + col] = (TC)(acc[ii][jj][r] + bv);
                }
            }
        }
    }
}

// ------------------------- MFMA flash attention ----------------------------
// grid = (head 8, batch 64, side 2). side 0: head-q x tail-k; side 1: swap.
__global__ __launch_bounds__(256) void attn_mfma(
    const __bf16* __restrict__ Q0, const __bf16* __restrict__ K0,
    const __bf16* __restrict__ Vr0, const __bf16* __restrict__ Vc0,
    const __bf16* __restrict__ Q1, const __bf16* __restrict__ K1,
    const __bf16* __restrict__ Vr1, const __bf16* __restrict__ Vc1,
    const int* __restrict__ ranges,
    __bf16* __restrict__ O0, __bf16* __restrict__ O1,
    int Nq, int Nk)
{
    __shared__ __align__(16) __bf16 Qs[64][72];
    __shared__ __align__(16) __bf16 Ks[64][72];
    __shared__ __align__(16) __bf16 Vt[64][72];   // [dim][key]
    __shared__ __align__(16) __bf16 Ps[64][72];   // [query][key]

    const int z = blockIdx.z;
    const __bf16* Q    = z ? Q1 : Q0;
    const __bf16* Kg   = z ? K1 : K0;
    const __bf16* Vres = z ? Vr1 : Vr0;
    const __bf16* Vctx = z ? Vc1 : Vc0;
    __bf16* Out        = z ? O1 : O0;
    const int* qstart  = z ? ranges + 128 : ranges;
    const int* qend    = z ? ranges + 192 : ranges + 64;
    const int* kstart  = z ? ranges       : ranges + 128;
    const int* kend    = z ? ranges + 64  : ranges + 192;

    const int h = blockIdx.x, b = blockIdx.y;
    const int qs = qstart[b], qe = qend[b];
    const int ts = kstart[b], te = kend[b];
    const int nq = qe - qs, nk = te - ts;
    if (nq <= 0) return;

    const int tid  = threadIdx.x;
    const int wave = tid >> 6;
    const int lane = tid & 63;
    const int quad = lane >> 4;
    const int l16  = lane & 15;
    const int srow = tid >> 2;
    const int scol = (tid & 3) * 16;

    if (nk <= 0) {
        float* meanv = (float*)Qs;
        if (tid < 64) {
            float s = 0.f;
            for (int m = 0; m < Nk; ++m)
                s += (float)Vctx[(size_t)m * HID + h * 64 + tid];
            meanv[tid] = s / (float)Nk;
        }
        __syncthreads();
        int d = tid & 63;
        for (int r = qs + (tid >> 6); r < qe; r += 4) {
            size_t off = (size_t)r * HID + h * 64 + d;
            Out[off] = (__bf16)((float)Vres[off] + meanv[d]);
        }
        return;
    }

    for (int qc = 0; qc < nq; qc += 64) {
        __syncthreads();
        {
            int qg = min(qs + qc + srow, Nq - 1);
            const __bf16* src = Q + (size_t)qg * HID + h * 64 + scol;
            *(bf16x8*)&Qs[srow][scol]     = *(const bf16x8*)src;
            *(bf16x8*)&Qs[srow][scol + 8] = *(const bf16x8*)(src + 8);
        }
        __syncthreads();
        bf16x8 aq0 = *(const bf16x8*)&Qs[wave * 16 + l16][quad * 8];
        bf16x8 aq1 = *(const bf16x8*)&Qs[wave * 16 + l16][32 + quad * 8];

        f32x4 O[4] = {};
        float Mx[4], L[4];
        #pragma unroll
        for (int r = 0; r < 4; ++r) { Mx[r] = -__builtin_inff(); L[r] = 0.f; }

        for (int kc = 0; kc < nk; kc += 64) {
            __syncthreads();
            {
                int kg = min(ts + kc + srow, Nk - 1);
                const __bf16* ksrc = Kg + (size_t)kg * HID + h * 64 + scol;
                *(bf16x8*)&Ks[srow][scol]     = *(const bf16x8*)ksrc;
                *(bf16x8*)&Ks[srow][scol + 8] = *(const bf16x8*)(ksrc + 8);
                const __bf16* vsrc = Vctx + (size_t)kg * HID + h * 64 + scol;
                bf16x8 v0 = *(const bf16x8*)vsrc;
                bf16x8 v1 = *(const bf16x8*)(vsrc + 8);
                #pragma unroll
                for (int j = 0; j < 8; ++j) {
                    Vt[scol + j][srow]     = v0[j];
                    Vt[scol + 8 + j][srow] = v1[j];
                }
            }
            __syncthreads();

            f32x4 S[4] = {};
            #pragma unroll
            for (int c = 0; c < 4; ++c) {
                bf16x8 bk0 = *(const bf16x8*)&Ks[c * 16 + l16][quad * 8];
                bf16x8 bk1 = *(const bf16x8*)&Ks[c * 16 + l16][32 + quad * 8];
                S[c] = __builtin_amdgcn_mfma_f32_16x16x32_bf16(aq0, bk0, S[c], 0, 0, 0);
                S[c] = __builtin_amdgcn_mfma_f32_16x16x32_bf16(aq1, bk1, S[c], 0, 0, 0);
            }

            #pragma unroll
            for (int c = 0; c < 4; ++c) {
                bool valid = (ts + kc + c * 16 + l16) < te;
                #pragma unroll
                for (int r = 0; r < 4; ++r)
                    S[c][r] = valid ? S[c][r] * 0.125f : -__builtin_inff();
            }

            float cm[4], ps[4], alpha[4];
            #pragma unroll
            for (int r = 0; r < 4; ++r) {
                float v = fmaxf(fmaxf(S[0][r], S[1][r]), fmaxf(S[2][r], S[3][r]));
                v = fmaxf(v, __shfl_xor(v, 1, 64));
                v = fmaxf(v, __shfl_xor(v, 2, 64));
                v = fmaxf(v, __shfl_xor(v, 4, 64));
                v = fmaxf(v, __shfl_xor(v, 8, 64));
                cm[r] = v;
            }
            #pragma unroll
            for (int r = 0; r < 4; ++r) {
                float nM = fmaxf(Mx[r], cm[r]);
                alpha[r] = __expf(Mx[r] - nM);
                Mx[r] = nM;
                ps[r] = 0.f;
            }
            #pragma unroll
            for (int c = 0; c < 4; ++c)
                #pragma unroll
                for (int r = 0; r < 4; ++r) {
                    float p = __expf(S[c][r] - Mx[r]);
                    S[c][r] = p;
                    ps[r] += p;
                }
            #pragma unroll
            for (int r = 0; r < 4; ++r) {
                float v = ps[r];
                v += __shfl_xor(v, 1, 64);
                v += __shfl_xor(v, 2, 64);
                v += __shfl_xor(v, 4, 64);
                v += __shfl_xor(v, 8, 64);
                L[r] = L[r] * alpha[r] + v;
            }
            #pragma unroll
            for (int c = 0; c < 4; ++c)
                #pragma unroll
                for (int r = 0; r < 4; ++r)
                    O[c][r] *= alpha[r];

            #pragma unroll
            for (int c = 0; c < 4; ++c)
                #pragma unroll
                for (int r = 0; r < 4; ++r)
                    Ps[wave * 16 + quad * 4 + r][c * 16 + l16] = (__bf16)S[c][r];
            __syncthreads();

            bf16x8 ap0 = *(const bf16x8*)&Ps[wave * 16 + l16][quad * 8];
            bf16x8 ap1 = *(const bf16x8*)&Ps[wave * 16 + l16][32 + quad * 8];
            #pragma unroll
            for (int c = 0; c < 4; ++c) {
                bf16x8 bv0 = *(const bf16x8*)&Vt[c * 16 + l16][quad * 8];
                bf16x8 bv1 = *(const bf16x8*)&Vt[c * 16 + l16][32 + quad * 8];
                O[c] = __builtin_amdgcn_mfma_f32_16x16x32_bf16(ap0, bv0, O[c], 0, 0, 0);
                O[c] = __builtin_amdgcn_mfma_f32_16x16x32_bf16(ap1, bv1, O[c], 0, 0, 0);
            }
        }

        #pragma unroll
        for (int c = 0; c < 4; ++c) {
            int d = h * 64 + c * 16 + l16;
            #pragma unroll
            for (int r = 0; r < 4; ++r) {
                int qrow = qs + qc + wave * 16 + quad * 4 + r;
                if (qrow < qe) {
                    size_t off = (size_t)qrow * HID + d;
                    Out[off] = (__bf16)((float)Vres[off] + O[c][r] / L[r]);
                }
            }
        }
    }
}

// ------------------------------ launcher -----------------------------------
extern "C" void kernel_launch(void* const* d_in, const int* in_sizes, int n_in,
                              void* d_out, int out_size, void* d_ws, size_t ws_size,
                              hipStream_t stream) {
    (void)in_sizes; (void)n_in; (void)out_size; (void)ws_size;

    const float* h_head = (const float*)d_in[0];
    const float* h_tail = (const float*)d_in[1];
    const int* batch_head = (const int*)d_in[2];
    const int* batch_tail = (const int*)d_in[3];
    const float* map_w = (const float*)d_in[4];
    const float* map_b = (const float*)d_in[5];
    const float* q1_w = (const float*)d_in[6];
    const float* q1_b = (const float*)d_in[7];
    const float* k1_w = (const float*)d_in[8];
    const float* k1_b = (const float*)d_in[9];
    const float* v1_w = (const float*)d_in[10];
    const float* v1_b = (const float*)d_in[11];
    const float* q2_w = (const float*)d_in[12];
    const float* q2_b = (const float*)d_in[13];
    const float* k2_w = (const float*)d_in[14];
    const float* k2_b = (const float*)d_in[15];
    const float* v2_w = (const float*)d_in[16];
    const float* v2_b = (const float*)d_in[17];
    const float* d1_w = (const float*)d_in[18];
    const float* d1_b = (const float*)d_in[19];
    const float* d2_w = (const float*)d_in[20];
    const float* d2_b = (const float*)d_in[21];

    float* out = (float*)d_out;

    const size_t SZ = (size_t)NTOK * HID;
    char* ws = (char*)d_ws;
    int* ranges   = (int*)ws;                            // 1 KB
    __bf16* hh_bf = (__bf16*)(ws + 1024);                // [4096][320]
    __bf16* ht_bf = hh_bf + (size_t)NTOK * 320;          // [4096][512]
    __bf16* mapw_bf = ht_bf + SZ;                        // [384][512]
    __bf16* q1T  = mapw_bf + 384 * 512;                  // [512][512] each
    __bf16* k1T  = q1T + 512 * 512;
    __bf16* v1T  = k1T + 512 * 512;
    __bf16* q2T  = v1T + 512 * 512;
    __bf16* k2T  = q2T + 512 * 512;
    __bf16* v2T  = k2T + 512 * 512;
    __bf16* d1T  = v2T + 512 * 512;
    __bf16* d2T  = d1T + 512 * 512;
    __bf16* FqT  = d2T + 512 * 512;                      // [512][320] each
    __bf16* FkT  = FqT + 512 * 320;
    __bf16* FvT  = FkT + 512 * 320;
    __bf16* qh   = FvT + 512 * 320;                      // [4096][512] each
    __bf16* kh   = qh  + SZ;
    __bf16* vh   = kh  + SZ;
    __bf16* qt   = vh  + SZ;
    __bf16* kt   = qt  + SZ;
    __bf16* vt   = kt  + SZ;
    __bf16* ctxh = vt  + SZ;
    __bf16* ctxt = ctxh + SZ;
    float*  fb   = (float*)(ctxt + SZ);                  // [3][512] fp32

    // D1: prep + all transposes + map cast + bias fold
    PrepArgs pa;
    pa.h_head = h_head; pa.h_tail = h_tail;
    pa.bh = batch_head; pa.bt = batch_tail;
    pa.map_w = map_w; pa.map_b = map_b;
    pa.qkvw[0] = q1_w; pa.qkvw[1] = k1_w; pa.qkvw[2] = v1_w;
    pa.qkvb[0] = q1_b; pa.qkvb[1] = k1_b; pa.qkvb[2] = v1_b;
    const float* wsrc[8] = {q1_w, k1_w, v1_w, q2_w, k2_w, v2_w, d1_w, d2_w};
    __bf16* wdst[8] = {q1T, k1T, v1T, q2T, k2T, v2T, d1T, d2T};
    for (int i = 0; i < 8; ++i) { pa.tsrc[i] = wsrc[i]; pa.tdst[i] = wdst[i]; }
    pa.hh_bf = hh_bf; pa.ht_bf = ht_bf; pa.mapw_bf = mapw_bf;
    pa.fb = fb; pa.ranges = ranges;
    fused_prep<<<dim3(512, 1, 11), dim3(256), 0, stream>>>(pa);

    // D2: fold GEMMs  FxT[n][k] = sum_j xT[n][j] * mapw_bf[k][j]
    //     = (map_w @ x_w)[k][n]   -> [512][320] bf16
    {
        GemmJobs j;
        const __bf16* a3[3] = {q1T, k1T, v1T};
        __bf16* c3[3] = {FqT, FkT, FvT};
        for (int i = 0; i < 6; ++i) {
            int s = i < 3 ? i : 0;
            j.A[i] = a3[s]; j.W[i] = mapw_bf; j.bias[i] = nullptr;
            j.C[i] = c3[s]; j.Kp[i] = 512; j.ldC[i] = 320; j.Ncol[i] = 320;
        }
        gemm128<__bf16><<<dim3(3, 4, 3), dim3(256), 0, stream>>>(j);
    }

    // D3: all six qkv GEMMs concurrently
    {
        GemmJobs j;
        j.A[0] = hh_bf; j.W[0] = FqT; j.bias[0] = fb;        j.C[0] = qh; j.Kp[0] = 320;
        j.A[1] = hh_bf; j.W[1] = FkT; j.bias[1] = fb + 512;  j.C[1] = kh; j.Kp[1] = 320;
        j.A[2] = hh_bf; j.W[2] = FvT; j.bias[2] = fb + 1024; j.C[2] = vh; j.Kp[2] = 320;
        j.A[3] = ht_bf; j.W[3] = q2T; j.bias[3] = q2_b;      j.C[3] = qt; j.Kp[3] = 512;
        j.A[4] = ht_bf; j.W[4] = k2T; j.bias[4] = k2_b;      j.C[4] = kt; j.Kp[4] = 512;
        j.A[5] = ht_bf; j.W[5] = v2T; j.bias[5] = v2_b;      j.C[5] = vt; j.Kp[5] = 512;
        for (int i = 0; i < 6; ++i) { j.ldC[i] = HID; j.Ncol[i] = HID; }
        gemm128<__bf16><<<dim3(4, 32, 6), dim3(256), 0, stream>>>(j);
    }

    // D4: attention (both sides, one dispatch)
    attn_mfma<<<dim3(8, 64, 2), dim3(256), 0, stream>>>(
        qh, kt, vh, vt,
        qt, kh, vt, vh,
        ranges, ctxh, ctxt, NTOK, NTOK);

    // D5: output projections (fp32 into d_out)
    {
        GemmJobs j;
        for (int i = 0; i < 6; ++i) {
            int s = i < 2 ? i : 0;
            j.A[i] = s ? ctxt : ctxh;
            j.W[i] = s ? d2T : d1T;
            j.bias[i] = s ? d2_b : d1_b;
            j.C[i] = s ? (void*)(out + SZ) : (void*)out;
            j.Kp[i] = 512; j.ldC[i] = HID; j.Ncol[i] = HID;
        }
        gemm128<float><<<dim3(4, 32, 2), dim3(256), 0, stream>>>(j);
    }
}